// Round 4
// baseline (462.691 us; speedup 1.0000x reference)
//
#include <hip/hip_runtime.h>

#define U 128
#define UV 32          // U/4 float4s
#define NSEG 4
#define NPATH 20
#define ROW (NSEG * UV)  // 128 float4 per batch row

// Kernel 1: collapse the 20 (i0,i1,i2,coef) paths into dense W[s2][a][b] (64 floats).
__global__ void build_w_kernel(const float* __restrict__ coef,
                               const int* __restrict__ idx,
                               float* __restrict__ W) {
    int j = threadIdx.x;
    if (j >= 64) return;
    int s2 = j >> 4;
    int a  = (j >> 2) & 3;
    int b  = j & 3;
    float w = 0.0f;
    for (int p = 0; p < NPATH; ++p) {
        int i0 = idx[p * 3 + 0];
        int i1 = idx[p * 3 + 1];
        int i2 = idx[p * 3 + 2];
        if (i0 == a && i1 == b && i2 == s2) w += coef[p];
    }
    W[j] = w;
}

__device__ __forceinline__ void tp_loads(const float4* __restrict__ x0,
                                         const float4* __restrict__ x1,
                                         int base,
                                         float4 (&a)[NSEG], float4 (&c)[NSEG]) {
#pragma unroll
    for (int s = 0; s < NSEG; ++s) a[s] = x0[base + s * UV];
#pragma unroll
    for (int s = 0; s < NSEG; ++s) c[s] = x1[base + s * UV];
}

// out[s2] = sum_a a[a] * (sum_b W[s2][a][b] * c[b]); plain float4 store.
__device__ __forceinline__ void tp_compute_store(const float4 (&a)[NSEG],
                                                 const float4 (&c)[NSEG],
                                                 const float* __restrict__ W,
                                                 float4* __restrict__ out,
                                                 int base) {
#pragma unroll
    for (int s2 = 0; s2 < NSEG; ++s2) {
        float4 acc = make_float4(0.f, 0.f, 0.f, 0.f);
#pragma unroll
        for (int aa = 0; aa < NSEG; ++aa) {
            float4 tv = make_float4(0.f, 0.f, 0.f, 0.f);
#pragma unroll
            for (int bb = 0; bb < NSEG; ++bb) {
                float wv = W[s2 * 16 + aa * 4 + bb];   // wave-uniform -> SGPR
                tv.x = fmaf(wv, c[bb].x, tv.x);
                tv.y = fmaf(wv, c[bb].y, tv.y);
                tv.z = fmaf(wv, c[bb].z, tv.z);
                tv.w = fmaf(wv, c[bb].w, tv.w);
            }
            acc.x = fmaf(a[aa].x, tv.x, acc.x);
            acc.y = fmaf(a[aa].y, tv.y, acc.y);
            acc.z = fmaf(a[aa].z, tv.z, acc.z);
            acc.w = fmaf(a[aa].w, tv.w, acc.w);
        }
        out[base + s2 * UV] = acc;   // plain store (nt regressed 16% in R1)
    }
}

// Kernel 2: persistent grid-stride waves, 2-deep software pipeline.
// Iteration i+1's 8 loads are issued BEFORE compute/store of iteration i,
// so every wave keeps 8 loads in flight through its compute phase.
__global__ __launch_bounds__(256) void tp_main_kernel(const float4* __restrict__ x0,
                                                      const float4* __restrict__ x1,
                                                      const float* __restrict__ W,
                                                      float4* __restrict__ out,
                                                      int total) {
    const int T = gridDim.x * 256;          // total threads (multiple of 64)
    int t = blockIdx.x * 256 + threadIdx.x;
    if (t >= total) return;

    float4 a[NSEG], c[NSEG], an[NSEG], cn[NSEG];
    int base = (t >> 5) * ROW + (t & 31);
    tp_loads(x0, x1, base, a, c);           // prologue

    for (;;) {
        int tn = t + T;
        bool more = tn < total;             // wave-uniform: total % 64 == 0
        int basen = (tn >> 5) * ROW + (tn & 31);
        if (more) tp_loads(x0, x1, basen, an, cn);   // prefetch next tile

        tp_compute_store(a, c, W, out, base);        // consume current tile

        if (!more) break;
        t = tn; base = basen;
#pragma unroll
        for (int s = 0; s < NSEG; ++s) { a[s] = an[s]; c[s] = cn[s]; }
    }
}

extern "C" void kernel_launch(void* const* d_in, const int* in_sizes, int n_in,
                              void* d_out, int out_size, void* d_ws, size_t ws_size,
                              hipStream_t stream) {
    const float* x0   = (const float*)d_in[0];
    const float* x1   = (const float*)d_in[1];
    const float* coef = (const float*)d_in[2];
    const int*   idx  = (const int*)d_in[3];
    float* W = (float*)d_ws;

    int batch = in_sizes[0] / (NSEG * U);
    int total = batch * UV;                 // one thread-task per (batch, u-quad)

    // Persistent grid: 2048 blocks (8 wg/CU ceiling; VGPR will cap residency),
    // grid-stride covers the remainder (~6 iterations/thread).
    int grid = 2048;
    int need = (total + 255) / 256;
    if (need < grid) grid = need;

    build_w_kernel<<<1, 64, 0, stream>>>(coef, idx, W);
    tp_main_kernel<<<grid, 256, 0, stream>>>(
        (const float4*)x0, (const float4*)x1, W, (float4*)d_out, total);
}

// Round 5
// 457.646 us; speedup vs baseline: 1.0110x; 1.0110x over previous
//
#include <hip/hip_runtime.h>

#define U 128
#define UV 32            // U/4 float4s
#define NSEG 4
#define NPATH 20
#define ROWF4 (NSEG * UV)  // 128 float4 per batch row (2 KB)

// Kernel 1: collapse the 20 (i0,i1,i2,coef) paths into dense W[s2][a][b] (64 floats).
__global__ void build_w_kernel(const float* __restrict__ coef,
                               const int* __restrict__ idx,
                               float* __restrict__ W) {
    int j = threadIdx.x;
    if (j >= 64) return;
    int s2 = j >> 4;
    int a  = (j >> 2) & 3;
    int b  = j & 3;
    float w = 0.0f;
    for (int p = 0; p < NPATH; ++p) {
        int i0 = idx[p * 3 + 0];
        int i1 = idx[p * 3 + 1];
        int i2 = idx[p * 3 + 2];
        if (i0 == a && i1 == b && i2 == s2) w += coef[p];
    }
    W[j] = w;
}

__device__ __forceinline__ float4 shfl_xor32(float4 v) {
    float4 r;
    r.x = __shfl_xor(v.x, 32, 64);
    r.y = __shfl_xor(v.y, 32, 64);
    r.z = __shfl_xor(v.z, 32, 64);
    r.w = __shfl_xor(v.w, 32, 64);
    return r;
}

// Kernel 2: one WAVE per batch row pair-of-halves; every global load/store is a
// single contiguous 1 KB segment (copy-kernel-identical burst shape).
// Lane l holds segs {h, 2+h} at u=l&31 (h=l>>5); partner lane l^32 holds {1-h, 3-h}.
__global__ __launch_bounds__(256) void tp_main_kernel(const float4* __restrict__ x0,
                                                      const float4* __restrict__ x1,
                                                      const float* __restrict__ W,
                                                      float4* __restrict__ out,
                                                      int total) {
    int t = blockIdx.x * 256 + threadIdx.x;
    if (t >= total) return;      // total % 64 == 0: whole waves only
    int b = t >> 6;              // batch row
    int l = t & 63;              // lane within wave
    int h = l >> 5;              // half-wave: 0 -> segs {0,2}, 1 -> segs {1,3}
    int base = b * ROWF4;

    // Four 1 KB contiguous wave-loads (lane l -> base + l, base + 64 + l).
    float4 xa = x0[base + l];        // x0 seg h,   u = l&31
    float4 xb = x0[base + 64 + l];   // x0 seg 2+h
    float4 ya = x1[base + l];        // x1 seg h
    float4 yb = x1[base + 64 + l];   // x1 seg 2+h

    // Partner exchange: fetch segs {1-h, 3-h} from lane l^32 (same u).
    float4 xap = shfl_xor32(xa);
    float4 xbp = shfl_xor32(xb);
    float4 yap = shfl_xor32(ya);
    float4 ybp = shfl_xor32(yb);

    // Assemble segment-ordered operands (per-lane select, 4 cndmask each).
    float4 a0 = h ? xap : xa;    // seg 0
    float4 a1 = h ? xa  : xap;   // seg 1
    float4 a2 = h ? xbp : xb;    // seg 2
    float4 a3 = h ? xb  : xbp;   // seg 3
    float4 c0 = h ? yap : ya;
    float4 c1 = h ? ya  : yap;
    float4 c2 = h ? yb  : ybp;   // careful: seg 2 of x1
    float4 c3 = h ? ybp : yb;    // seg 3 of x1
    // fix: same pattern as a2/a3
    c2 = h ? ybp : yb;           // seg 2
    c3 = h ? yb  : ybp;         // seg 3

    const float4 a[NSEG] = {a0, a1, a2, a3};
    const float4 c[NSEG] = {c0, c1, c2, c3};

    // Compute all 4 output segs (redundant across half-waves; VALU is cheap here).
    float4 acc[NSEG];
#pragma unroll
    for (int s2 = 0; s2 < NSEG; ++s2) {
        float4 r = make_float4(0.f, 0.f, 0.f, 0.f);
#pragma unroll
        for (int aa = 0; aa < NSEG; ++aa) {
            float4 tv = make_float4(0.f, 0.f, 0.f, 0.f);
#pragma unroll
            for (int bb = 0; bb < NSEG; ++bb) {
                float wv = W[s2 * 16 + aa * 4 + bb];   // wave-uniform -> SGPR
                tv.x = fmaf(wv, c[bb].x, tv.x);
                tv.y = fmaf(wv, c[bb].y, tv.y);
                tv.z = fmaf(wv, c[bb].z, tv.z);
                tv.w = fmaf(wv, c[bb].w, tv.w);
            }
            r.x = fmaf(a[aa].x, tv.x, r.x);
            r.y = fmaf(a[aa].y, tv.y, r.y);
            r.z = fmaf(a[aa].z, tv.z, r.z);
            r.w = fmaf(a[aa].w, tv.w, r.w);
        }
        acc[s2] = r;
    }

    // Two 1 KB contiguous wave-stores: slot base+l is seg h, slot base+64+l is seg 2+h.
    float4 o1 = h ? acc[1] : acc[0];
    float4 o2 = h ? acc[3] : acc[2];
    out[base + l]      = o1;
    out[base + 64 + l] = o2;
}

extern "C" void kernel_launch(void* const* d_in, const int* in_sizes, int n_in,
                              void* d_out, int out_size, void* d_ws, size_t ws_size,
                              hipStream_t stream) {
    const float* x0   = (const float*)d_in[0];
    const float* x1   = (const float*)d_in[1];
    const float* coef = (const float*)d_in[2];
    const int*   idx  = (const int*)d_in[3];
    float* W = (float*)d_ws;

    int batch = in_sizes[0] / (NSEG * U);
    int total = batch * 64;      // one thread per (batch, lane); 64 lanes cover a 2 KB row

    build_w_kernel<<<1, 64, 0, stream>>>(coef, idx, W);
    tp_main_kernel<<<(total + 255) / 256, 256, 0, stream>>>(
        (const float4*)x0, (const float4*)x1, W, (float4*)d_out, total);
}